// Round 7
// baseline (238.361 us; speedup 1.0000x reference)
//
#include <hip/hip_runtime.h>
#include <hip/hip_bf16.h>

typedef __bf16 bf16;
typedef __bf16 bf16x8 __attribute__((ext_vector_type(8)));
typedef float f32x4 __attribute__((ext_vector_type(4)));

#define MFMA16(a, b, c) __builtin_amdgcn_mfma_f32_16x16x32_bf16((a), (b), (c), 0, 0, 0)

// async global->LDS, 16B per lane; LDS dest = wave-uniform base + lane*16.
__device__ __forceinline__ void async16(const void* g, void* l) {
  typedef const unsigned int __attribute__((address_space(1))) * GP;
  typedef unsigned int __attribute__((address_space(3))) * LP;
  __builtin_amdgcn_global_load_lds((GP)g, (LP)l, 16, 0, 0);
}

// ---- DPP 16-lane row sum (epilogue only) -----------------------------------
template <int ctrl>
__device__ __forceinline__ float dppf(float v) {
  return __builtin_bit_cast(
      float, __builtin_amdgcn_update_dpp(0, __builtin_bit_cast(int, v), ctrl,
                                         0xf, 0xf, true));
}
__device__ __forceinline__ float rowsum16(float x) {
  x += dppf<0xB1>(x);
  x += dppf<0x4E>(x);
  x += dppf<0x141>(x);
  x += dppf<0x140>(x);
  return x;
}

// ---------------------------------------------------------------------------
// Convert x: fp32 [4M] -> bf16 [4M].
// ---------------------------------------------------------------------------
__global__ __launch_bounds__(256) void convert_x(
    const float* __restrict__ src, bf16* __restrict__ dst) {
  int i = (blockIdx.x * 256 + threadIdx.x) * 4;
  f32x4 v = *(const f32x4*)&src[i];
  bf16 o[4];
#pragma unroll
  for (int j = 0; j < 4; ++j) o[j] = (bf16)v[j];
  *(ulong1*)&dst[i] = *(ulong1*)o;
}

// ---------------------------------------------------------------------------
// Transpose+convert 4 weight matrices fp32 [1024x1024] -> bf16 Wt[n][k].
// ---------------------------------------------------------------------------
__global__ __launch_bounds__(256) void transpose_w(
    const float* __restrict__ w0, const float* __restrict__ w1,
    const float* __restrict__ w2, const float* __restrict__ w3,
    bf16* __restrict__ out) {
  __shared__ __align__(16) float tile[64][68];
  const float* src = (blockIdx.z == 0) ? w0 : (blockIdx.z == 1) ? w1
                   : (blockIdx.z == 2) ? w2 : w3;
  bf16* dst = out + (size_t)blockIdx.z * (1024u * 1024u);
  const int t = threadIdx.x;
  const int bx = blockIdx.x, by = blockIdx.y;

#pragma unroll
  for (int p = 0; p < 4; ++p) {
    int idx = t + p * 256;
    int r = idx >> 4, c4 = idx & 15;
    *(f32x4*)&tile[r][c4 * 4] =
        *(const f32x4*)&src[(size_t)(by * 64 + r) * 1024 + bx * 64 + c4 * 4];
  }
  __syncthreads();
#pragma unroll
  for (int p = 0; p < 2; ++p) {
    int idx = t + p * 256;
    int rn = idx >> 3, c8 = idx & 7;
    bf16x8 v;
#pragma unroll
    for (int i = 0; i < 8; ++i) v[i] = (bf16)tile[c8 * 8 + i][rn];
    *(bf16x8*)&dst[(size_t)(bx * 64 + rn) * 1024 + by * 64 + c8 * 8] = v;
  }
}

// ---------------------------------------------------------------------------
// Transpose V per head: v[b][s][h*64+d] -> vt[(b*16+h)][d][s]  (bf16).
// ---------------------------------------------------------------------------
__global__ __launch_bounds__(256) void transpose_v(
    const bf16* __restrict__ v, bf16* __restrict__ vt) {
  __shared__ __align__(16) bf16 t[64][72];
  const int st = blockIdx.x, h = blockIdx.y, b = blockIdx.z;
  const int tid = threadIdx.x;
  const bf16* src = v + ((size_t)b * 2048) * 1024 + (size_t)h * 64;
  bf16* dst = vt + ((size_t)(b * 16 + h)) * 64 * 2048;
#pragma unroll
  for (int p = 0; p < 2; ++p) {
    int idx = tid + p * 256, r = idx >> 3, c = idx & 7;
    *(bf16x8*)&t[r][c * 8] =
        *(const bf16x8*)&src[(size_t)(st * 64 + r) * 1024 + c * 8];
  }
  __syncthreads();
#pragma unroll
  for (int p = 0; p < 2; ++p) {
    int idx = tid + p * 256, d = idx >> 3, c = idx & 7;
    bf16x8 o;
#pragma unroll
    for (int i = 0; i < 8; ++i) o[i] = t[c * 8 + i][d];
    *(bf16x8*)&dst[(size_t)d * 2048 + st * 64 + c * 8] = o;
  }
}

// ---------------------------------------------------------------------------
// GEMM: C[M x 1024] = A[M x 1024] @ W (Bt[n][k]), BK=64, global_load_lds
// staging, XOR-swizzled unpadded LDS: lds[row][cg] = global[row][cg^(row&7)].
// z==0 output scaled by scaleZ0 (folds softmax 1/8*log2e into Q).
// grid: (N/128, M/128, nz).
// ---------------------------------------------------------------------------
template <typename OutT>
__global__ __launch_bounds__(256) void gemm_bt(
    const bf16* __restrict__ A, const bf16* __restrict__ Bt,
    OutT* __restrict__ C, int btStrideZ, int cStrideZ, float scaleZ0) {
  const int tid = threadIdx.x;
  const int wave = tid >> 6, lane = tid & 63;
  const int quad = lane >> 4, l16 = lane & 15;
  const int wm = wave >> 1, wn = wave & 1;
  const int m0 = blockIdx.y * 128, n0 = blockIdx.x * 128;
  const bf16* Bz = Bt + (size_t)blockIdx.z * (size_t)btStrideZ;
  OutT* Cz = C + (size_t)blockIdx.z * (size_t)cStrideZ;
  const float sc = (blockIdx.z == 0) ? scaleZ0 : 1.0f;

  __shared__ __align__(16) bf16 lsA[128 * 64];  // swizzled, 16KB
  __shared__ __align__(16) bf16 lsB[128 * 64];

  const int lrow = lane >> 3;         // 0..7 within 8-row chunk
  const int cgX = (lane & 7) ^ lrow;  // swizzled col-group to fetch

  f32x4 acc[4][4];
#pragma unroll
  for (int i = 0; i < 4; ++i)
#pragma unroll
    for (int j = 0; j < 4; ++j) acc[i][j] = (f32x4){0.f, 0.f, 0.f, 0.f};

  for (int k0 = 0; k0 < 1024; k0 += 64) {
    __syncthreads();
#pragma unroll
    for (int c = 0; c < 4; ++c) {
      int chunk = wave * 4 + c;  // 0..15, 8 rows each
      int row = chunk * 8 + lrow;
      async16(&A[(size_t)(m0 + row) * 1024 + k0 + cgX * 8], &lsA[chunk * 512]);
      async16(&Bz[(size_t)(n0 + row) * 1024 + k0 + cgX * 8], &lsB[chunk * 512]);
    }
    __syncthreads();

#pragma unroll
    for (int ks = 0; ks < 2; ++ks) {
      bf16x8 af[4], bfr[4];
#pragma unroll
      for (int i = 0; i < 4; ++i) {
        int ra = wm * 64 + i * 16 + l16;
        af[i] =
            *(const bf16x8*)&lsA[ra * 64 + (((ks * 4 + quad) ^ (l16 & 7)) * 8)];
        int rb = wn * 64 + i * 16 + l16;
        bfr[i] =
            *(const bf16x8*)&lsB[rb * 64 + (((ks * 4 + quad) ^ (l16 & 7)) * 8)];
      }
#pragma unroll
      for (int mi = 0; mi < 4; ++mi)
#pragma unroll
        for (int ni = 0; ni < 4; ++ni)
          acc[mi][ni] = MFMA16(af[mi], bfr[ni], acc[mi][ni]);
    }
  }

#pragma unroll
  for (int mi = 0; mi < 4; ++mi)
#pragma unroll
    for (int ni = 0; ni < 4; ++ni) {
      int col = n0 + wn * 64 + ni * 16 + l16;
#pragma unroll
      for (int r = 0; r < 4; ++r) {
        int row = m0 + wm * 64 + mi * 16 + quad * 4 + r;
        Cz[(size_t)row * 1024 + col] = (OutT)(acc[mi][ni][r] * sc);
      }
    }
}

// ---------------------------------------------------------------------------
// Flash attention, q-tile = 128 rows/block (2 strips of 16 rows per wave ->
// 32 MFMA per staged 64-key tile). Fixed-max softmax (Q pre-scaled by
// 0.125*log2e -> p = exp2(s)). K/V via global_load_lds + XOR swizzle.
// Ps overlays QsPs with stride 64 and the SAME XOR swizzle (fits 128x64).
// grid: (16, H, B) = 512 blocks, qt = 15 - blockIdx.x (big first).
// ---------------------------------------------------------------------------
__global__ __launch_bounds__(256) void attn_fwd(
    const bf16* __restrict__ Q, const bf16* __restrict__ K,
    const bf16* __restrict__ Vt, bf16* __restrict__ O) {
  const int qt = 15 - (int)blockIdx.x;
  const int h = blockIdx.y, b = blockIdx.z;
  const int tid = threadIdx.x;
  const int wave = tid >> 6, lane = tid & 63;
  const int quad = lane >> 4, l16 = lane & 15;

  __shared__ __align__(16) bf16 QsPs[128 * 64];  // Q then Ps, both swizzled
  __shared__ __align__(16) bf16 Ks[64 * 64];     // swizzled
  __shared__ __align__(16) bf16 Vs[64 * 64];     // swizzled, [d][s-window]

  const size_t base = ((size_t)b * 2048) * 1024 + (size_t)h * 64;
  const bf16* Qb = Q + base;
  const bf16* Kb = K + base;
  const bf16* Vtb = Vt + ((size_t)(b * 16 + h)) * 64 * 2048;
  bf16* Ob = O + base;

  const int lrow = lane >> 3;
  const int cgX = (lane & 7) ^ lrow;

  // stage Q tile (128 x 64), already scaled by 0.125*log2e from the GEMM
#pragma unroll
  for (int c = 0; c < 4; ++c) {
    int chunk = wave * 4 + c;
    int row = chunk * 8 + lrow;
    async16(&Qb[(size_t)(qt * 128 + row) * 1024 + cgX * 8],
            &QsPs[chunk * 512]);
  }
  __syncthreads();
  bf16x8 aq[2][2];
#pragma unroll
  for (int s = 0; s < 2; ++s)
#pragma unroll
    for (int ks = 0; ks < 2; ++ks) {
      int row = s * 64 + wave * 16 + l16;
      aq[s][ks] = *(const bf16x8*)&QsPs[row * 64 +
                                        (((ks * 4 + quad) ^ (l16 & 7)) * 8)];
    }

  const float NEG_INF = -__builtin_inff();
  float ls_acc[2][4] = {{0.f, 0.f, 0.f, 0.f}, {0.f, 0.f, 0.f, 0.f}};
  f32x4 Oacc[2][4];
#pragma unroll
  for (int s = 0; s < 2; ++s)
#pragma unroll
    for (int nt = 0; nt < 4; ++nt) Oacc[s][nt] = (f32x4){0.f, 0.f, 0.f, 0.f};

  bf16* Psp = &QsPs[0];  // swizzled [128][64] overlay (Q frags in registers)
  const int kt_end = 2 * qt + 1;

  for (int kt = 0; kt <= kt_end; ++kt) {
    __syncthreads();  // all waves done reading Ks/Vs of previous tile
#pragma unroll
    for (int c = 0; c < 2; ++c) {
      int chunk = wave * 2 + c;
      int row = chunk * 8 + lrow;
      async16(&Kb[(size_t)(kt * 64 + row) * 1024 + cgX * 8], &Ks[chunk * 512]);
      async16(&Vtb[(size_t)row * 2048 + kt * 64 + cgX * 8], &Vs[chunk * 512]);
    }
    __syncthreads();  // vmcnt(0) drain -> K/V present

    bf16x8 bk[4][2];
#pragma unroll
    for (int nt = 0; nt < 4; ++nt)
#pragma unroll
      for (int ks = 0; ks < 2; ++ks) {
        int row = nt * 16 + l16;
        bk[nt][ks] = *(const bf16x8*)&Ks[row * 64 +
                                         (((ks * 4 + quad) ^ (l16 & 7)) * 8)];
      }

#pragma unroll
    for (int s = 0; s < 2; ++s) {
      if (s == 0 && kt == kt_end) continue;  // strip0 fully masked last iter
      f32x4 sv[4];
#pragma unroll
      for (int nt = 0; nt < 4; ++nt) {
        sv[nt] = (f32x4){0.f, 0.f, 0.f, 0.f};
        sv[nt] = MFMA16(aq[s][0], bk[nt][0], sv[nt]);
        sv[nt] = MFMA16(aq[s][1], bk[nt][1], sv[nt]);
      }
      if (kt == 2 * qt + s) {  // diagonal tile for this strip
        const int rowb = wave * 16 + quad * 4;
#pragma unroll
        for (int nt = 0; nt < 4; ++nt) {
          const int col = nt * 16 + l16;
#pragma unroll
          for (int r = 0; r < 4; ++r)
            if (col > rowb + r) sv[nt][r] = NEG_INF;
        }
      }
#pragma unroll
      for (int nt = 0; nt < 4; ++nt)
#pragma unroll
        for (int r = 0; r < 4; ++r) {
          float p = exp2f(sv[nt][r]);
          sv[nt][r] = p;
          ls_acc[s][r] += p;
        }
      // P: C/D-layout -> A-layout via swizzled LDS (wave-private rows)
#pragma unroll
      for (int nt = 0; nt < 4; ++nt) {
        const int col = nt * 16 + l16;
        const int cg = col >> 3;
#pragma unroll
        for (int r = 0; r < 4; ++r) {
          int prow = s * 64 + wave * 16 + quad * 4 + r;
          Psp[prow * 64 + ((cg ^ (prow & 7)) * 8) + (col & 7)] =
              (bf16)sv[nt][r];
        }
      }
    }

    bf16x8 bv[4][2];
#pragma unroll
    for (int nt = 0; nt < 4; ++nt)
#pragma unroll
      for (int ks = 0; ks < 2; ++ks) {
        int row = nt * 16 + l16;
        bv[nt][ks] = *(const bf16x8*)&Vs[row * 64 +
                                         (((ks * 4 + quad) ^ (l16 & 7)) * 8)];
      }
#pragma unroll
    for (int s = 0; s < 2; ++s) {
      if (s == 0 && kt == kt_end) continue;
      int arow = s * 64 + wave * 16 + l16;
      bf16x8 ap0 =
          *(const bf16x8*)&Psp[arow * 64 + (((0 + quad) ^ (l16 & 7)) * 8)];
      bf16x8 ap1 =
          *(const bf16x8*)&Psp[arow * 64 + (((4 + quad) ^ (l16 & 7)) * 8)];
#pragma unroll
      for (int nt = 0; nt < 4; ++nt) {
        Oacc[s][nt] = MFMA16(ap0, bv[nt][0], Oacc[s][nt]);
        Oacc[s][nt] = MFMA16(ap1, bv[nt][1], Oacc[s][nt]);
      }
    }
  }

  // epilogue: one DPP reduction for l per strip, normalize, store
#pragma unroll
  for (int s = 0; s < 2; ++s) {
    float rl[4];
#pragma unroll
    for (int r = 0; r < 4; ++r) rl[r] = 1.f / rowsum16(ls_acc[s][r]);
#pragma unroll
    for (int nt = 0; nt < 4; ++nt)
#pragma unroll
      for (int r = 0; r < 4; ++r) {
        int row = qt * 128 + s * 64 + wave * 16 + quad * 4 + r;
        Ob[(size_t)row * 1024 + nt * 16 + l16] =
            (bf16)(Oacc[s][nt][r] * rl[r]);
      }
  }
}

// ---------------------------------------------------------------------------
// Launch
// ---------------------------------------------------------------------------
extern "C" void kernel_launch(void* const* d_in, const int* in_sizes, int n_in,
                              void* d_out, int out_size, void* d_ws,
                              size_t ws_size, hipStream_t stream) {
  (void)in_sizes; (void)n_in; (void)out_size; (void)ws_size;
  const float* x  = (const float*)d_in[0];
  const float* Wq = (const float*)d_in[1];
  const float* Wk = (const float*)d_in[2];
  const float* Wv = (const float*)d_in[3];
  const float* Wo = (const float*)d_in[4];
  float* out = (float*)d_out;

  bf16* ws = (bf16*)d_ws;
  const size_t WELEM = 1024u * 1024u;
  const size_t TELEM = 4096u * 1024u;
  bf16* wt  = ws;               // 4 transposed weights (8 MB)
  bf16* xbf = ws + 4 * WELEM;   // x bf16 (8 MB) — reused as vt after QKV
  bf16* q   = xbf + TELEM;
  bf16* k   = q + TELEM;
  bf16* v   = k + TELEM;
  bf16* ao  = v + TELEM;
  bf16* vt  = xbf;  // safe: xbf last read by QKV GEMM, before transpose_v

  const float QSCALE = 0.125f * 1.44269504088896340736f;  // 1/sqrt(64)*log2e

  convert_x<<<dim3(4096), 256, 0, stream>>>(x, xbf);
  transpose_w<<<dim3(16, 16, 4), 256, 0, stream>>>(Wq, Wk, Wv, Wo, wt);
  gemm_bt<bf16><<<dim3(8, 32, 3), 256, 0, stream>>>(xbf, wt, q, (int)WELEM,
                                                    (int)TELEM, QSCALE);
  transpose_v<<<dim3(32, 16, 2), 256, 0, stream>>>(v, vt);
  attn_fwd<<<dim3(16, 16, 2), 256, 0, stream>>>(q, k, vt, ao);
  gemm_bt<float><<<dim3(8, 32, 1), 256, 0, stream>>>(ao, wt + 3 * WELEM, out,
                                                     0, 0, 1.0f);
}

// Round 8
// 208.268 us; speedup vs baseline: 1.1445x; 1.1445x over previous
//
#include <hip/hip_runtime.h>
#include <hip/hip_bf16.h>

typedef __bf16 bf16;
typedef __bf16 bf16x8 __attribute__((ext_vector_type(8)));
typedef float f32x4 __attribute__((ext_vector_type(4)));

#define MFMA16(a, b, c) __builtin_amdgcn_mfma_f32_16x16x32_bf16((a), (b), (c), 0, 0, 0)

// async global->LDS, 16B per lane; LDS dest = wave-uniform base + lane*16.
__device__ __forceinline__ void async16(const void* g, void* l) {
  typedef const unsigned int __attribute__((address_space(1))) * GP;
  typedef unsigned int __attribute__((address_space(3))) * LP;
  __builtin_amdgcn_global_load_lds((GP)g, (LP)l, 16, 0, 0);
}

// ---- DPP 16-lane row sum (epilogue only) -----------------------------------
template <int ctrl>
__device__ __forceinline__ float dppf(float v) {
  return __builtin_bit_cast(
      float, __builtin_amdgcn_update_dpp(0, __builtin_bit_cast(int, v), ctrl,
                                         0xf, 0xf, true));
}
__device__ __forceinline__ float rowsum16(float x) {
  x += dppf<0xB1>(x);
  x += dppf<0x4E>(x);
  x += dppf<0x141>(x);
  x += dppf<0x140>(x);
  return x;
}

// ---------------------------------------------------------------------------
// Convert x: fp32 [4M] -> bf16 [4M].
// ---------------------------------------------------------------------------
__global__ __launch_bounds__(256) void convert_x(
    const float* __restrict__ src, bf16* __restrict__ dst) {
  int i = (blockIdx.x * 256 + threadIdx.x) * 4;
  f32x4 v = *(const f32x4*)&src[i];
  bf16 o[4];
#pragma unroll
  for (int j = 0; j < 4; ++j) o[j] = (bf16)v[j];
  *(ulong1*)&dst[i] = *(ulong1*)o;
}

// ---------------------------------------------------------------------------
// Transpose+convert 4 weight matrices fp32 [1024x1024] -> bf16 Wt[n][k].
// ---------------------------------------------------------------------------
__global__ __launch_bounds__(256) void transpose_w(
    const float* __restrict__ w0, const float* __restrict__ w1,
    const float* __restrict__ w2, const float* __restrict__ w3,
    bf16* __restrict__ out) {
  __shared__ __align__(16) float tile[64][68];
  const float* src = (blockIdx.z == 0) ? w0 : (blockIdx.z == 1) ? w1
                   : (blockIdx.z == 2) ? w2 : w3;
  bf16* dst = out + (size_t)blockIdx.z * (1024u * 1024u);
  const int t = threadIdx.x;
  const int bx = blockIdx.x, by = blockIdx.y;

#pragma unroll
  for (int p = 0; p < 4; ++p) {
    int idx = t + p * 256;
    int r = idx >> 4, c4 = idx & 15;
    *(f32x4*)&tile[r][c4 * 4] =
        *(const f32x4*)&src[(size_t)(by * 64 + r) * 1024 + bx * 64 + c4 * 4];
  }
  __syncthreads();
#pragma unroll
  for (int p = 0; p < 2; ++p) {
    int idx = t + p * 256;
    int rn = idx >> 3, c8 = idx & 7;
    bf16x8 v;
#pragma unroll
    for (int i = 0; i < 8; ++i) v[i] = (bf16)tile[c8 * 8 + i][rn];
    *(bf16x8*)&dst[(size_t)(bx * 64 + rn) * 1024 + by * 64 + c8 * 8] = v;
  }
}

// ---------------------------------------------------------------------------
// Transpose V per head: v[b][s][h*64+d] -> vt[(b*16+h)][d][s]  (bf16).
// ---------------------------------------------------------------------------
__global__ __launch_bounds__(256) void transpose_v(
    const bf16* __restrict__ v, bf16* __restrict__ vt) {
  __shared__ __align__(16) bf16 t[64][72];
  const int st = blockIdx.x, h = blockIdx.y, b = blockIdx.z;
  const int tid = threadIdx.x;
  const bf16* src = v + ((size_t)b * 2048) * 1024 + (size_t)h * 64;
  bf16* dst = vt + ((size_t)(b * 16 + h)) * 64 * 2048;
#pragma unroll
  for (int p = 0; p < 2; ++p) {
    int idx = tid + p * 256, r = idx >> 3, c = idx & 7;
    *(bf16x8*)&t[r][c * 8] =
        *(const bf16x8*)&src[(size_t)(st * 64 + r) * 1024 + c * 8];
  }
  __syncthreads();
#pragma unroll
  for (int p = 0; p < 2; ++p) {
    int idx = tid + p * 256, d = idx >> 3, c = idx & 7;
    bf16x8 o;
#pragma unroll
    for (int i = 0; i < 8; ++i) o[i] = t[c * 8 + i][d];
    *(bf16x8*)&dst[(size_t)d * 2048 + st * 64 + c * 8] = o;
  }
}

// ---------------------------------------------------------------------------
// GEMM: C[M x 1024] = A[M x 1024] @ W (Bt[n][k]), BK=64, global_load_lds
// staging, XOR-swizzled unpadded LDS: lds[row][cg] = global[row][cg^(row&7)].
// z==0 output scaled by scaleZ0 (folds softmax 1/8*log2e into Q).
// grid: (N/128, M/128, nz).
// ---------------------------------------------------------------------------
template <typename OutT>
__global__ __launch_bounds__(256) void gemm_bt(
    const bf16* __restrict__ A, const bf16* __restrict__ Bt,
    OutT* __restrict__ C, int btStrideZ, int cStrideZ, float scaleZ0) {
  const int tid = threadIdx.x;
  const int wave = tid >> 6, lane = tid & 63;
  const int quad = lane >> 4, l16 = lane & 15;
  const int wm = wave >> 1, wn = wave & 1;
  const int m0 = blockIdx.y * 128, n0 = blockIdx.x * 128;
  const bf16* Bz = Bt + (size_t)blockIdx.z * (size_t)btStrideZ;
  OutT* Cz = C + (size_t)blockIdx.z * (size_t)cStrideZ;
  const float sc = (blockIdx.z == 0) ? scaleZ0 : 1.0f;

  __shared__ __align__(16) bf16 lsA[128 * 64];  // swizzled, 16KB
  __shared__ __align__(16) bf16 lsB[128 * 64];

  const int lrow = lane >> 3;         // 0..7 within 8-row chunk
  const int cgX = (lane & 7) ^ lrow;  // swizzled col-group to fetch

  f32x4 acc[4][4];
#pragma unroll
  for (int i = 0; i < 4; ++i)
#pragma unroll
    for (int j = 0; j < 4; ++j) acc[i][j] = (f32x4){0.f, 0.f, 0.f, 0.f};

  for (int k0 = 0; k0 < 1024; k0 += 64) {
    __syncthreads();
#pragma unroll
    for (int c = 0; c < 4; ++c) {
      int chunk = wave * 4 + c;  // 0..15, 8 rows each
      int row = chunk * 8 + lrow;
      async16(&A[(size_t)(m0 + row) * 1024 + k0 + cgX * 8], &lsA[chunk * 512]);
      async16(&Bz[(size_t)(n0 + row) * 1024 + k0 + cgX * 8], &lsB[chunk * 512]);
    }
    __syncthreads();

#pragma unroll
    for (int ks = 0; ks < 2; ++ks) {
      bf16x8 af[4], bfr[4];
#pragma unroll
      for (int i = 0; i < 4; ++i) {
        int ra = wm * 64 + i * 16 + l16;
        af[i] =
            *(const bf16x8*)&lsA[ra * 64 + (((ks * 4 + quad) ^ (l16 & 7)) * 8)];
        int rb = wn * 64 + i * 16 + l16;
        bfr[i] =
            *(const bf16x8*)&lsB[rb * 64 + (((ks * 4 + quad) ^ (l16 & 7)) * 8)];
      }
#pragma unroll
      for (int mi = 0; mi < 4; ++mi)
#pragma unroll
        for (int ni = 0; ni < 4; ++ni)
          acc[mi][ni] = MFMA16(af[mi], bfr[ni], acc[mi][ni]);
    }
  }

#pragma unroll
  for (int mi = 0; mi < 4; ++mi)
#pragma unroll
    for (int ni = 0; ni < 4; ++ni) {
      int col = n0 + wn * 64 + ni * 16 + l16;
#pragma unroll
      for (int r = 0; r < 4; ++r) {
        int row = m0 + wm * 64 + mi * 16 + quad * 4 + r;
        Cz[(size_t)row * 1024 + col] = (OutT)(acc[mi][ni][r] * sc);
      }
    }
}

// ---------------------------------------------------------------------------
// Flash attention, 64-row q-tile per block, 4 waves x 16 q-rows.
// Fixed-max softmax (Q pre-scaled by 0.125*log2e -> p = exp2(s)).
// K/V DOUBLE-BUFFERED: prefetch tile kt+1 via global_load_lds before
// computing tile kt; single __syncthreads per tile (its vmcnt/lgkm drain
// lands after a full tile of compute -> staging latency hidden).
// 1D grid of 1024 blocks with balance swizzle: co-resident blocks
// (bid +-256/512) get qt sets {a, 31-a, a, 31-a} -> uniform 66 tiles/CU.
// LDS 40KB -> 4 blocks/CU (16 waves/CU).
// ---------------------------------------------------------------------------
__global__ __launch_bounds__(256, 4) void attn_fwd(
    const bf16* __restrict__ Q, const bf16* __restrict__ K,
    const bf16* __restrict__ Vt, bf16* __restrict__ O) {
  const int bid = blockIdx.x;
  const int x = bid & 31, hb = bid >> 5;
  const int qt = ((hb >> 3) & 1) ? (31 - x) : x;  // CU-level balance swizzle
  const int h = hb & 15, b = hb >> 4;
  const int tid = threadIdx.x;
  const int wave = tid >> 6, lane = tid & 63;
  const int quad = lane >> 4, l16 = lane & 15;

  __shared__ __align__(16) bf16 QsPs[64 * 64];   // Q then Ps, swizzled
  __shared__ __align__(16) bf16 Ks[2][64 * 64];  // double-buffered, swizzled
  __shared__ __align__(16) bf16 Vs[2][64 * 64];  // dbuf, swizzled, [d][s]

  const size_t base = ((size_t)b * 2048) * 1024 + (size_t)h * 64;
  const bf16* Qb = Q + base;
  const bf16* Kb = K + base;
  const bf16* Vtb = Vt + ((size_t)(b * 16 + h)) * 64 * 2048;
  bf16* Ob = O + base;

  const int lrow = lane >> 3;
  const int cgX = (lane & 7) ^ lrow;

  // stage Q (64x64, pre-scaled by 0.125*log2e in the QKV GEMM) + K/V tile 0
#pragma unroll
  for (int c = 0; c < 2; ++c) {
    int chunk = wave * 2 + c;  // 8 chunks x 8 rows
    int row = chunk * 8 + lrow;
    async16(&Qb[(size_t)(qt * 64 + row) * 1024 + cgX * 8],
            &QsPs[chunk * 512]);
    async16(&Kb[(size_t)(row) * 1024 + cgX * 8], &Ks[0][chunk * 512]);
    async16(&Vtb[(size_t)row * 2048 + cgX * 8], &Vs[0][chunk * 512]);
  }
  __syncthreads();

  bf16x8 aq[2];
#pragma unroll
  for (int ks = 0; ks < 2; ++ks) {
    int row = wave * 16 + l16;
    aq[ks] =
        *(const bf16x8*)&QsPs[row * 64 + (((ks * 4 + quad) ^ (l16 & 7)) * 8)];
  }

  const float NEG_INF = -__builtin_inff();
  float ls_acc[4] = {0.f, 0.f, 0.f, 0.f};
  f32x4 Oacc[4];
#pragma unroll
  for (int nt = 0; nt < 4; ++nt) Oacc[nt] = (f32x4){0.f, 0.f, 0.f, 0.f};

  bf16* Psp = &QsPs[0];  // swizzled [64][64] overlay (Q frags in registers)

  for (int kt = 0; kt <= qt; ++kt) {
    const int cur = kt & 1;
    // prefetch next K/V tile into the other buffer (latency hidden by the
    // compute below; drained by the barrier at the end of this iteration)
    if (kt < qt) {
#pragma unroll
      for (int c = 0; c < 2; ++c) {
        int chunk = wave * 2 + c;
        int row = chunk * 8 + lrow;
        async16(&Kb[(size_t)((kt + 1) * 64 + row) * 1024 + cgX * 8],
                &Ks[cur ^ 1][chunk * 512]);
        async16(&Vtb[(size_t)row * 2048 + (kt + 1) * 64 + cgX * 8],
                &Vs[cur ^ 1][chunk * 512]);
      }
    }

    // S = Q K^T : 16 q-rows x 64 k-cols per wave
    bf16x8 bk[4][2];
#pragma unroll
    for (int nt = 0; nt < 4; ++nt)
#pragma unroll
      for (int ks = 0; ks < 2; ++ks) {
        int row = nt * 16 + l16;
        bk[nt][ks] = *(const bf16x8*)&Ks[cur][row * 64 +
                                             (((ks * 4 + quad) ^ (l16 & 7)) *
                                              8)];
      }
    f32x4 sv[4];
#pragma unroll
    for (int nt = 0; nt < 4; ++nt) {
      sv[nt] = (f32x4){0.f, 0.f, 0.f, 0.f};
      sv[nt] = MFMA16(aq[0], bk[nt][0], sv[nt]);
      sv[nt] = MFMA16(aq[1], bk[nt][1], sv[nt]);
    }

    if (kt == qt) {  // causal mask on the diagonal tile
      const int rowb = wave * 16 + quad * 4;
#pragma unroll
      for (int nt = 0; nt < 4; ++nt) {
        const int col = nt * 16 + l16;
#pragma unroll
        for (int r = 0; r < 4; ++r)
          if (col > rowb + r) sv[nt][r] = NEG_INF;
      }
    }
#pragma unroll
    for (int nt = 0; nt < 4; ++nt)
#pragma unroll
      for (int r = 0; r < 4; ++r) {
        float p = exp2f(sv[nt][r]);
        sv[nt][r] = p;
        ls_acc[r] += p;
      }

    // P: C/D-layout -> A-layout via swizzled LDS (wave-private 16-row band)
#pragma unroll
    for (int nt = 0; nt < 4; ++nt) {
      const int col = nt * 16 + l16;
      const int cg = col >> 3;
#pragma unroll
      for (int r = 0; r < 4; ++r) {
        int prow = wave * 16 + quad * 4 + r;
        Psp[prow * 64 + ((cg ^ (prow & 7)) * 8) + (col & 7)] = (bf16)sv[nt][r];
      }
    }

    bf16x8 bv[4][2];
#pragma unroll
    for (int nt = 0; nt < 4; ++nt)
#pragma unroll
      for (int ks = 0; ks < 2; ++ks) {
        int row = nt * 16 + l16;
        bv[nt][ks] = *(const bf16x8*)&Vs[cur][row * 64 +
                                             (((ks * 4 + quad) ^ (l16 & 7)) *
                                              8)];
      }
    const int arow = wave * 16 + l16;
    bf16x8 ap0 = *(const bf16x8*)&Psp[arow * 64 + ((quad ^ (l16 & 7)) * 8)];
    bf16x8 ap1 =
        *(const bf16x8*)&Psp[arow * 64 + (((4 + quad) ^ (l16 & 7)) * 8)];
#pragma unroll
    for (int nt = 0; nt < 4; ++nt) {
      Oacc[nt] = MFMA16(ap0, bv[nt][0], Oacc[nt]);
      Oacc[nt] = MFMA16(ap1, bv[nt][1], Oacc[nt]);
    }

    __syncthreads();  // drains prefetch (vmcnt) + publishes Ks/Vs[cur] free
  }

  // epilogue: one DPP reduction for l, normalize, store
  float rl[4];
#pragma unroll
  for (int r = 0; r < 4; ++r) rl[r] = 1.f / rowsum16(ls_acc[r]);
#pragma unroll
  for (int nt = 0; nt < 4; ++nt)
#pragma unroll
    for (int r = 0; r < 4; ++r) {
      int row = qt * 64 + wave * 16 + quad * 4 + r;
      Ob[(size_t)row * 1024 + nt * 16 + l16] = (bf16)(Oacc[nt][r] * rl[r]);
    }
}

// ---------------------------------------------------------------------------
// Launch
// ---------------------------------------------------------------------------
extern "C" void kernel_launch(void* const* d_in, const int* in_sizes, int n_in,
                              void* d_out, int out_size, void* d_ws,
                              size_t ws_size, hipStream_t stream) {
  (void)in_sizes; (void)n_in; (void)out_size; (void)ws_size;
  const float* x  = (const float*)d_in[0];
  const float* Wq = (const float*)d_in[1];
  const float* Wk = (const float*)d_in[2];
  const float* Wv = (const float*)d_in[3];
  const float* Wo = (const float*)d_in[4];
  float* out = (float*)d_out;

  bf16* ws = (bf16*)d_ws;
  const size_t WELEM = 1024u * 1024u;
  const size_t TELEM = 4096u * 1024u;
  bf16* wt  = ws;               // 4 transposed weights (8 MB)
  bf16* xbf = ws + 4 * WELEM;   // x bf16 (8 MB) — reused as vt after QKV
  bf16* q   = xbf + TELEM;
  bf16* k   = q + TELEM;
  bf16* v   = k + TELEM;
  bf16* ao  = v + TELEM;
  bf16* vt  = xbf;  // safe: xbf last read by QKV GEMM, before transpose_v

  const float QSCALE = 0.125f * 1.44269504088896340736f;  // 1/sqrt(64)*log2e

  convert_x<<<dim3(4096), 256, 0, stream>>>(x, xbf);
  transpose_w<<<dim3(16, 16, 4), 256, 0, stream>>>(Wq, Wk, Wv, Wo, wt);
  gemm_bt<bf16><<<dim3(8, 32, 3), 256, 0, stream>>>(xbf, wt, q, (int)WELEM,
                                                    (int)TELEM, QSCALE);
  transpose_v<<<dim3(32, 16, 2), 256, 0, stream>>>(v, vt);
  attn_fwd<<<dim3(1024), 256, 0, stream>>>(q, k, vt, ao);
  gemm_bt<float><<<dim3(8, 32, 1), 256, 0, stream>>>(ao, wt + 3 * WELEM, out,
                                                     0, 0, 1.0f);
}

// Round 9
// 195.512 us; speedup vs baseline: 1.2192x; 1.0652x over previous
//
#include <hip/hip_runtime.h>
#include <hip/hip_bf16.h>

typedef __bf16 bf16;
typedef __bf16 bf16x8 __attribute__((ext_vector_type(8)));
typedef float f32x4 __attribute__((ext_vector_type(4)));

#define MFMA16(a, b, c) __builtin_amdgcn_mfma_f32_16x16x32_bf16((a), (b), (c), 0, 0, 0)

// async global->LDS, 16B per lane; LDS dest = wave-uniform base + lane*16.
__device__ __forceinline__ void async16(const void* g, void* l) {
  typedef const unsigned int __attribute__((address_space(1))) * GP;
  typedef unsigned int __attribute__((address_space(3))) * LP;
  __builtin_amdgcn_global_load_lds((GP)g, (LP)l, 16, 0, 0);
}

// ---- DPP 16-lane row sum (epilogue only) -----------------------------------
template <int ctrl>
__device__ __forceinline__ float dppf(float v) {
  return __builtin_bit_cast(
      float, __builtin_amdgcn_update_dpp(0, __builtin_bit_cast(int, v), ctrl,
                                         0xf, 0xf, true));
}
__device__ __forceinline__ float rowsum16(float x) {
  x += dppf<0xB1>(x);
  x += dppf<0x4E>(x);
  x += dppf<0x141>(x);
  x += dppf<0x140>(x);
  return x;
}

// ---------------------------------------------------------------------------
// Convert x: fp32 [4M] -> bf16 [4M].
// ---------------------------------------------------------------------------
__global__ __launch_bounds__(256) void convert_x(
    const float* __restrict__ src, bf16* __restrict__ dst) {
  int i = (blockIdx.x * 256 + threadIdx.x) * 4;
  f32x4 v = *(const f32x4*)&src[i];
  bf16 o[4];
#pragma unroll
  for (int j = 0; j < 4; ++j) o[j] = (bf16)v[j];
  *(ulong1*)&dst[i] = *(ulong1*)o;
}

// ---------------------------------------------------------------------------
// Transpose+convert 4 weight matrices fp32 [1024x1024] -> bf16 Wt[n][k].
// ---------------------------------------------------------------------------
__global__ __launch_bounds__(256) void transpose_w(
    const float* __restrict__ w0, const float* __restrict__ w1,
    const float* __restrict__ w2, const float* __restrict__ w3,
    bf16* __restrict__ out) {
  __shared__ __align__(16) float tile[64][68];
  const float* src = (blockIdx.z == 0) ? w0 : (blockIdx.z == 1) ? w1
                   : (blockIdx.z == 2) ? w2 : w3;
  bf16* dst = out + (size_t)blockIdx.z * (1024u * 1024u);
  const int t = threadIdx.x;
  const int bx = blockIdx.x, by = blockIdx.y;

#pragma unroll
  for (int p = 0; p < 4; ++p) {
    int idx = t + p * 256;
    int r = idx >> 4, c4 = idx & 15;
    *(f32x4*)&tile[r][c4 * 4] =
        *(const f32x4*)&src[(size_t)(by * 64 + r) * 1024 + bx * 64 + c4 * 4];
  }
  __syncthreads();
#pragma unroll
  for (int p = 0; p < 2; ++p) {
    int idx = t + p * 256;
    int rn = idx >> 3, c8 = idx & 7;
    bf16x8 v;
#pragma unroll
    for (int i = 0; i < 8; ++i) v[i] = (bf16)tile[c8 * 8 + i][rn];
    *(bf16x8*)&dst[(size_t)(bx * 64 + rn) * 1024 + by * 64 + c8 * 8] = v;
  }
}

// ---------------------------------------------------------------------------
// Transpose V per head: v[b][s][h*64+d] -> vt[(b*16+h)][d][s]  (bf16).
// ---------------------------------------------------------------------------
__global__ __launch_bounds__(256) void transpose_v(
    const bf16* __restrict__ v, bf16* __restrict__ vt) {
  __shared__ __align__(16) bf16 t[64][72];
  const int st = blockIdx.x, h = blockIdx.y, b = blockIdx.z;
  const int tid = threadIdx.x;
  const bf16* src = v + ((size_t)b * 2048) * 1024 + (size_t)h * 64;
  bf16* dst = vt + ((size_t)(b * 16 + h)) * 64 * 2048;
#pragma unroll
  for (int p = 0; p < 2; ++p) {
    int idx = tid + p * 256, r = idx >> 3, c = idx & 7;
    *(bf16x8*)&t[r][c * 8] =
        *(const bf16x8*)&src[(size_t)(st * 64 + r) * 1024 + c * 8];
  }
  __syncthreads();
#pragma unroll
  for (int p = 0; p < 2; ++p) {
    int idx = tid + p * 256, d = idx >> 3, c = idx & 7;
    bf16x8 o;
#pragma unroll
    for (int i = 0; i < 8; ++i) o[i] = t[c * 8 + i][d];
    *(bf16x8*)&dst[(size_t)d * 2048 + st * 64 + c * 8] = o;
  }
}

// ---------------------------------------------------------------------------
// GEMM: C[M x 1024] = A[M x 1024] @ W (Bt[n][k]). BK=32, DOUBLE-BUFFERED
// global_load_lds staging with ONE barrier per K-step: prefetch k+1 into the
// alternate buffer before consuming k, so the barrier's vmcnt drain lands
// after 16 MFMA of compute. Swizzle f(row)=(row>>1)&3 -> 2-way reads (free).
// z==0 output scaled by scaleZ0 (folds softmax 1/8*log2e into Q).
// grid: (N/128, M/128, nz).
// ---------------------------------------------------------------------------
template <typename OutT>
__global__ __launch_bounds__(256, 4) void gemm_bt(
    const bf16* __restrict__ A, const bf16* __restrict__ Bt,
    OutT* __restrict__ C, int btStrideZ, int cStrideZ, float scaleZ0) {
  const int tid = threadIdx.x;
  const int wave = tid >> 6, lane = tid & 63;
  const int quad = lane >> 4, l16 = lane & 15;
  const int wm = wave >> 1, wn = wave & 1;
  const int m0 = blockIdx.y * 128, n0 = blockIdx.x * 128;
  const bf16* Bz = Bt + (size_t)blockIdx.z * (size_t)btStrideZ;
  OutT* Cz = C + (size_t)blockIdx.z * (size_t)cStrideZ;
  const float sc = (blockIdx.z == 0) ? scaleZ0 : 1.0f;

  __shared__ __align__(16) bf16 lsA[2][128 * 32];  // 8KB per buf
  __shared__ __align__(16) bf16 lsB[2][128 * 32];

  const int lrow = lane >> 2;                       // 0..15 in 16-row chunk
  const int cgX = (lane & 3) ^ ((lrow >> 1) & 3);   // swizzled col-group
  const int fR = (l16 >> 1) & 3;                    // read-side swizzle term

  f32x4 acc[4][4];
#pragma unroll
  for (int i = 0; i < 4; ++i)
#pragma unroll
    for (int j = 0; j < 4; ++j) acc[i][j] = (f32x4){0.f, 0.f, 0.f, 0.f};

  // preload K-step 0 into buffer 0
#pragma unroll
  for (int c = 0; c < 2; ++c) {
    int chunk = wave * 2 + c;  // 8 chunks x 16 rows
    int row = chunk * 16 + lrow;
    async16(&A[(size_t)(m0 + row) * 1024 + cgX * 8], &lsA[0][chunk * 512]);
    async16(&Bz[(size_t)(n0 + row) * 1024 + cgX * 8], &lsB[0][chunk * 512]);
  }
  __syncthreads();

  for (int it = 0; it < 32; ++it) {
    const int cur = it & 1;
    if (it < 31) {  // prefetch next K-step into the alternate buffer
      int k0n = (it + 1) * 32;
#pragma unroll
      for (int c = 0; c < 2; ++c) {
        int chunk = wave * 2 + c;
        int row = chunk * 16 + lrow;
        async16(&A[(size_t)(m0 + row) * 1024 + k0n + cgX * 8],
                &lsA[cur ^ 1][chunk * 512]);
        async16(&Bz[(size_t)(n0 + row) * 1024 + k0n + cgX * 8],
                &lsB[cur ^ 1][chunk * 512]);
      }
    }

    bf16x8 af[4], bfr[4];
#pragma unroll
    for (int i = 0; i < 4; ++i) {
      int ra = wm * 64 + i * 16 + l16;
      af[i] = *(const bf16x8*)&lsA[cur][ra * 32 + ((quad ^ fR) * 8)];
      int rb = wn * 64 + i * 16 + l16;
      bfr[i] = *(const bf16x8*)&lsB[cur][rb * 32 + ((quad ^ fR) * 8)];
    }
#pragma unroll
    for (int mi = 0; mi < 4; ++mi)
#pragma unroll
      for (int ni = 0; ni < 4; ++ni)
        acc[mi][ni] = MFMA16(af[mi], bfr[ni], acc[mi][ni]);

    __syncthreads();  // drains prefetch; publishes cur free for overwrite
  }

#pragma unroll
  for (int mi = 0; mi < 4; ++mi)
#pragma unroll
    for (int ni = 0; ni < 4; ++ni) {
      int col = n0 + wn * 64 + ni * 16 + l16;
#pragma unroll
      for (int r = 0; r < 4; ++r) {
        int row = m0 + wm * 64 + mi * 16 + quad * 4 + r;
        Cz[(size_t)row * 1024 + col] = (OutT)(acc[mi][ni][r] * sc);
      }
    }
}

// ---------------------------------------------------------------------------
// Flash attention: 512 threads, 128-row q-tile, 8 waves x 16 q-rows sharing
// each staged 64-key K/V tile (2x MFMA per barrier vs 64-row blocks).
// Fixed-max softmax (Q pre-scaled by 0.125*log2e -> p = exp2(s)).
// K/V double-buffered global_load_lds, one barrier per tile. Wave w's
// diagonal tile ktd = 2qt + (w>>2); waves skip compute for kt > ktd.
// grid 512: x=bid&15, hb=bid>>4, h=hb&15, b=hb>>4; qt = b ? 15-x : x
// (co-resident pair {bid, bid+256} -> qt {a, 15-a} -> uniform 34 tiles).
// LDS 48KB -> >=2 blocks/CU.
// ---------------------------------------------------------------------------
__global__ __launch_bounds__(512, 4) void attn_fwd(
    const bf16* __restrict__ Q, const bf16* __restrict__ K,
    const bf16* __restrict__ Vt, bf16* __restrict__ O) {
  const int bid = blockIdx.x;
  const int x = bid & 15, hb = bid >> 4;
  const int h = hb & 15, b = hb >> 4;
  const int qt = b ? (15 - x) : x;
  const int tid = threadIdx.x;
  const int wave = tid >> 6, lane = tid & 63;
  const int quad = lane >> 4, l16 = lane & 15;

  __shared__ __align__(16) bf16 QsPs[128 * 64];  // Q then Ps, swizzled, 16KB
  __shared__ __align__(16) bf16 Ks[2][64 * 64];  // dbuf, swizzled, 16KB
  __shared__ __align__(16) bf16 Vs[2][64 * 64];  // dbuf, swizzled, [d][s]

  const size_t base = ((size_t)b * 2048) * 1024 + (size_t)h * 64;
  const bf16* Qb = Q + base;
  const bf16* Kb = K + base;
  const bf16* Vtb = Vt + ((size_t)(b * 16 + h)) * 64 * 2048;
  bf16* Ob = O + base;

  const int lrow = lane >> 3;          // 0..7
  const int cgX = (lane & 7) ^ lrow;   // swizzled col-group

  // stage Q (128x64, pre-scaled by 0.125*log2e in QKV GEMM) + K/V tile 0
#pragma unroll
  for (int c = 0; c < 2; ++c) {
    int chunk = wave * 2 + c;  // 16 chunks x 8 rows
    int row = chunk * 8 + lrow;
    async16(&Qb[(size_t)(qt * 128 + row) * 1024 + cgX * 8],
            &QsPs[chunk * 512]);
  }
  {
    int row = wave * 8 + lrow;  // 8 chunks x 8 rows, one per wave
    async16(&Kb[(size_t)row * 1024 + cgX * 8], &Ks[0][wave * 512]);
    async16(&Vtb[(size_t)row * 2048 + cgX * 8], &Vs[0][wave * 512]);
  }
  __syncthreads();

  bf16x8 aq[2];
#pragma unroll
  for (int ks = 0; ks < 2; ++ks) {
    int row = wave * 16 + l16;
    aq[ks] =
        *(const bf16x8*)&QsPs[row * 64 + (((ks * 4 + quad) ^ (l16 & 7)) * 8)];
  }

  const float NEG_INF = -__builtin_inff();
  float ls_acc[4] = {0.f, 0.f, 0.f, 0.f};
  f32x4 Oacc[4];
#pragma unroll
  for (int nt = 0; nt < 4; ++nt) Oacc[nt] = (f32x4){0.f, 0.f, 0.f, 0.f};

  bf16* Psp = &QsPs[0];  // swizzled [128][64] overlay (Q frags in registers)
  const int kt_end = 2 * qt + 1;
  const int ktd = 2 * qt + (wave >> 2);  // this wave's diagonal tile

  for (int kt = 0; kt <= kt_end; ++kt) {
    const int cur = kt & 1;
    if (kt < kt_end) {  // prefetch next K/V tile into alternate buffer
      int row = wave * 8 + lrow;
      async16(&Kb[(size_t)((kt + 1) * 64 + row) * 1024 + cgX * 8],
              &Ks[cur ^ 1][wave * 512]);
      async16(&Vtb[(size_t)row * 2048 + (kt + 1) * 64 + cgX * 8],
              &Vs[cur ^ 1][wave * 512]);
    }

    if (kt <= ktd) {
      // S = Q K^T : 16 q-rows x 64 k-cols for this wave
      f32x4 sv[4];
#pragma unroll
      for (int nt = 0; nt < 4; ++nt) {
        int row = nt * 16 + l16;
        bf16x8 bk0 =
            *(const bf16x8*)&Ks[cur][row * 64 + ((quad ^ (l16 & 7)) * 8)];
        bf16x8 bk1 = *(const bf16x8*)&Ks[cur][row * 64 +
                                             (((4 + quad) ^ (l16 & 7)) * 8)];
        sv[nt] = (f32x4){0.f, 0.f, 0.f, 0.f};
        sv[nt] = MFMA16(aq[0], bk0, sv[nt]);
        sv[nt] = MFMA16(aq[1], bk1, sv[nt]);
      }

      if (kt == ktd) {  // causal mask on this wave's diagonal tile
        const int rowb = wave * 16 + quad * 4;        // row_rel base
        const int cb = (kt - 2 * qt) * 64;            // col_rel base
#pragma unroll
        for (int nt = 0; nt < 4; ++nt) {
          const int col = cb + nt * 16 + l16;
#pragma unroll
          for (int r = 0; r < 4; ++r)
            if (col > rowb + r) sv[nt][r] = NEG_INF;
        }
      }
#pragma unroll
      for (int nt = 0; nt < 4; ++nt)
#pragma unroll
        for (int r = 0; r < 4; ++r) {
          float p = exp2f(sv[nt][r]);
          sv[nt][r] = p;
          ls_acc[r] += p;
        }

      // P: C/D-layout -> A-layout via swizzled LDS (wave-private rows)
#pragma unroll
      for (int nt = 0; nt < 4; ++nt) {
        const int col = nt * 16 + l16;
        const int cg = col >> 3;
#pragma unroll
        for (int r = 0; r < 4; ++r) {
          int prow = wave * 16 + quad * 4 + r;
          Psp[prow * 64 + ((cg ^ (prow & 7)) * 8) + (col & 7)] =
              (bf16)sv[nt][r];
        }
      }

      const int arow = wave * 16 + l16;
      bf16x8 ap0 = *(const bf16x8*)&Psp[arow * 64 + ((quad ^ (l16 & 7)) * 8)];
      bf16x8 ap1 =
          *(const bf16x8*)&Psp[arow * 64 + (((4 + quad) ^ (l16 & 7)) * 8)];
#pragma unroll
      for (int nt = 0; nt < 4; ++nt) {
        int row = nt * 16 + l16;
        bf16x8 bv0 =
            *(const bf16x8*)&Vs[cur][row * 64 + ((quad ^ (l16 & 7)) * 8)];
        bf16x8 bv1 = *(const bf16x8*)&Vs[cur][row * 64 +
                                             (((4 + quad) ^ (l16 & 7)) * 8)];
        Oacc[nt] = MFMA16(ap0, bv0, Oacc[nt]);
        Oacc[nt] = MFMA16(ap1, bv1, Oacc[nt]);
      }
    }

    __syncthreads();  // drains prefetch; publishes buffers
  }

  // epilogue: one DPP reduction for l, normalize, store
  float rl[4];
#pragma unroll
  for (int r = 0; r < 4; ++r) rl[r] = 1.f / rowsum16(ls_acc[r]);
#pragma unroll
  for (int nt = 0; nt < 4; ++nt)
#pragma unroll
    for (int r = 0; r < 4; ++r) {
      int row = qt * 128 + wave * 16 + quad * 4 + r;
      Ob[(size_t)row * 1024 + nt * 16 + l16] = (bf16)(Oacc[nt][r] * rl[r]);
    }
}

// ---------------------------------------------------------------------------
// Launch
// ---------------------------------------------------------------------------
extern "C" void kernel_launch(void* const* d_in, const int* in_sizes, int n_in,
                              void* d_out, int out_size, void* d_ws,
                              size_t ws_size, hipStream_t stream) {
  (void)in_sizes; (void)n_in; (void)out_size; (void)ws_size;
  const float* x  = (const float*)d_in[0];
  const float* Wq = (const float*)d_in[1];
  const float* Wk = (const float*)d_in[2];
  const float* Wv = (const float*)d_in[3];
  const float* Wo = (const float*)d_in[4];
  float* out = (float*)d_out;

  bf16* ws = (bf16*)d_ws;
  const size_t WELEM = 1024u * 1024u;
  const size_t TELEM = 4096u * 1024u;
  bf16* wt  = ws;               // 4 transposed weights (8 MB)
  bf16* xbf = ws + 4 * WELEM;   // x bf16 (8 MB) — reused as vt after QKV
  bf16* q   = xbf + TELEM;
  bf16* k   = q + TELEM;
  bf16* v   = k + TELEM;
  bf16* ao  = v + TELEM;
  bf16* vt  = xbf;  // safe: xbf last read by QKV GEMM, before transpose_v

  const float QSCALE = 0.125f * 1.44269504088896340736f;  // 1/sqrt(64)*log2e

  convert_x<<<dim3(4096), 256, 0, stream>>>(x, xbf);
  transpose_w<<<dim3(16, 16, 4), 256, 0, stream>>>(Wq, Wk, Wv, Wo, wt);
  gemm_bt<bf16><<<dim3(8, 32, 3), 256, 0, stream>>>(xbf, wt, q, (int)WELEM,
                                                    (int)TELEM, QSCALE);
  transpose_v<<<dim3(32, 16, 2), 256, 0, stream>>>(v, vt);
  attn_fwd<<<dim3(512), 512, 0, stream>>>(q, k, vt, ao);
  gemm_bt<float><<<dim3(8, 32, 1), 256, 0, stream>>>(ao, wt + 3 * WELEM, out,
                                                     0, 0, 1.0f);
}